// Round 2
// baseline (277.014 us; speedup 1.0000x reference)
//
#include <hip/hip_runtime.h>
#include <stdint.h>

// GQA fused forward: B=2, S=1024, HIDDEN=2048, H=32, G=8, D=64, causal.
// I/O is float32 (per reference dtypes); internal compute uses bf16 MFMA
// (2%-relative threshold permits this). Mask input ignored (causal known).
//
// Pipeline:
//   0) cvt:       f32 -> bf16 copies of x, Wq, Wk, Wv, Wo in workspace
//   1) qkv_gemm:  x[2048,2048] @ {Wq,Wk,Wv}^T + bias -> q_ws[b,h,s,d], k/v_ws[b,g,s,d]
//   2) attn:      flash-style causal attention per (b,h,qtile64) -> a_ws[b,s,h*d] (bf16)
//   3) out_gemm:  a_ws @ Wo^T + bo -> d_out (f32)
//
// GEMM structure = measured m97 recipe: 128x128 tile, BK=64, global_load_lds
// width=16, XOR-swizzled LDS rows, mfma_f32_16x16x32_bf16, fp32 accum.

typedef __bf16 bf16_8 __attribute__((ext_vector_type(8)));
typedef float f32x4 __attribute__((ext_vector_type(4)));

__device__ __forceinline__ unsigned short f2bf(float f) {
  union { float f; unsigned int i; } c; c.f = f;
  unsigned int u = c.i;
  return (unsigned short)((u + 0x7fffu + ((u >> 16) & 1u)) >> 16);
}

// async 16B global->LDS. LDS dest is wave-uniform base + lane*16; chunk
// indexing (c = tid + i*256) satisfies that (lane-contiguous 16B chunks).
__device__ __forceinline__ void gl2lds16(const void* g, void* l) {
  __builtin_amdgcn_global_load_lds(
      (const __attribute__((address_space(1))) void*)g,
      (__attribute__((address_space(3))) void*)l, 16, 0, 0);
}

// Stage a ROWS x 64 bf16 tile (row-major, leading dim ldg) into LDS with
// per-row XOR swizzle of 8-element groups: phys_group = log_group ^ (row&7).
template <int ROWS>
__device__ __forceinline__ void stage_tile(const unsigned short* g, int ldg,
                                           unsigned short* lds, int tid) {
#pragma unroll
  for (int i = 0; i < ROWS * 8 / 256; ++i) {
    int c = tid + i * 256;
    int r = c >> 3;
    int grp = (c & 7) ^ (r & 7);
    gl2lds16(g + (size_t)r * ldg + grp * 8, lds + c * 8);
  }
}

// Core 128x128 GEMM tile: Y = X[128,K] @ W[128,K]^T accumulated in acc[4][4].
__device__ __forceinline__ void gemm_core(const unsigned short* Xt,
                                          const unsigned short* Wt, int K,
                                          int tid, unsigned short* sA,
                                          unsigned short* sB, f32x4 acc[4][4]) {
  const int wave = tid >> 6, lane = tid & 63;
  const int wm = (wave >> 1) << 6, wn = (wave & 1) << 6;
  const int lrow = lane & 15, quad = lane >> 4;
  for (int k0 = 0; k0 < K; k0 += 64) {
    __syncthreads();  // prev-iter LDS reads done before restaging
    stage_tile<128>(Xt + k0, K, sA, tid);
    stage_tile<128>(Wt + k0, K, sB, tid);
    __syncthreads();  // staging visible (compiler drains vmcnt before barrier)
#pragma unroll
    for (int ks = 0; ks < 2; ++ks) {
      bf16_8 af[4], bw[4];
#pragma unroll
      for (int i = 0; i < 4; ++i) {
        int ra = wm + i * 16 + lrow;
        af[i] = *(const bf16_8*)(sA + ra * 64 + (((ks << 2) + quad) ^ (ra & 7)) * 8);
        int rb = wn + i * 16 + lrow;
        bw[i] = *(const bf16_8*)(sB + rb * 64 + (((ks << 2) + quad) ^ (rb & 7)) * 8);
      }
#pragma unroll
      for (int i = 0; i < 4; ++i)
#pragma unroll
        for (int j = 0; j < 4; ++j)
          acc[i][j] = __builtin_amdgcn_mfma_f32_16x16x32_bf16(af[i], bw[j],
                                                              acc[i][j], 0, 0, 0);
    }
  }
}

// ---------------- kernel 0: f32 -> bf16 conversion ----------------
// grid (4096, 5): y selects tensor {x, Wq, Wk, Wv, Wo}; 4 elems/thread.
__global__ void __launch_bounds__(256)
cvt_kernel(const float* __restrict__ s0, const float* __restrict__ s1,
           const float* __restrict__ s2, const float* __restrict__ s3,
           const float* __restrict__ s4,
           unsigned short* __restrict__ d0, unsigned short* __restrict__ d1,
           unsigned short* __restrict__ d2, unsigned short* __restrict__ d3,
           unsigned short* __restrict__ d4) {
  const float* src; unsigned short* dst; int n;
  switch (blockIdx.y) {
    case 0:  src = s0; dst = d0; n = 4194304; break;
    case 1:  src = s1; dst = d1; n = 4194304; break;
    case 2:  src = s2; dst = d2; n = 1048576; break;
    case 3:  src = s3; dst = d3; n = 1048576; break;
    default: src = s4; dst = d4; n = 4194304; break;
  }
  int idx = (blockIdx.x * 256 + threadIdx.x) * 4;
  if (idx >= n) return;
  float4 v = *(const float4*)(src + idx);
  ushort4 o;
  o.x = f2bf(v.x); o.y = f2bf(v.y); o.z = f2bf(v.z); o.w = f2bf(v.w);
  *(ushort4*)(dst + idx) = o;
}

// ---------------- kernel 1: fused QKV projection ----------------
// grid (16, 24): x = m-tile (128 rows of B*S), y = n-tile over [Q(16)|K(4)|V(4)]
__global__ void __launch_bounds__(256)
qkv_gemm(const unsigned short* __restrict__ X,
         const unsigned short* __restrict__ Wq, const float* __restrict__ bq,
         const unsigned short* __restrict__ Wk, const float* __restrict__ bk,
         const unsigned short* __restrict__ Wv, const float* __restrict__ bv,
         unsigned short* __restrict__ qws, unsigned short* __restrict__ kws,
         unsigned short* __restrict__ vws) {
  __shared__ unsigned short sA[128 * 64], sB[128 * 64];
  const int tid = threadIdx.x;
  const int tileM = blockIdx.x * 128;
  const int ty = blockIdx.y;
  const unsigned short* W;
  const float* bias;
  unsigned short* outp;
  int nbase, nh;
  if (ty < 16)      { W = Wq; bias = bq; outp = qws; nbase = ty * 128;        nh = 32; }
  else if (ty < 20) { W = Wk; bias = bk; outp = kws; nbase = (ty - 16) * 128; nh = 8; }
  else              { W = Wv; bias = bv; outp = vws; nbase = (ty - 20) * 128; nh = 8; }

  f32x4 acc[4][4] = {};
  gemm_core(X + (size_t)tileM * 2048, W + (size_t)nbase * 2048, 2048, tid, sA, sB, acc);

  const int wave = tid >> 6, lane = tid & 63;
  const int wm = (wave >> 1) << 6, wn = (wave & 1) << 6;
  const int lrow = lane & 15, quad = lane >> 4;
#pragma unroll
  for (int i = 0; i < 4; ++i)
#pragma unroll
    for (int j = 0; j < 4; ++j)
#pragma unroll
      for (int r = 0; r < 4; ++r) {
        int m = tileM + wm + i * 16 + quad * 4 + r;   // C row = m
        int n = nbase + wn + j * 16 + lrow;           // C col = n
        float v = acc[i][j][r] + bias[n];
        int b = m >> 10, s = m & 1023, h = n >> 6, d = n & 63;
        outp[((((size_t)b * nh + h) << 10) + s) * 64 + d] = f2bf(v);
      }
}

// ---------------- kernel 2: causal flash attention ----------------
// grid (16, 32, 2): (qtile, head, batch). 4 waves; wave w owns q-rows
// [16w,16w+16) of the 64-row tile. KV chunks of 64 up to the diagonal.
__global__ void __launch_bounds__(256)
attn_kernel(const unsigned short* __restrict__ Qw, const unsigned short* __restrict__ Kw,
            const unsigned short* __restrict__ Vw, unsigned short* __restrict__ Ow) {
  __shared__ unsigned short sQ[64 * 64], sK[64 * 64], sVt[64 * 64], sP[64 * 64];
  const int tid = threadIdx.x;
  const int qt = blockIdx.x, h = blockIdx.y, b = blockIdx.z;
  const int g = h >> 2;  // Q_PER_KV = 4
  const unsigned short* Qb = Qw + ((((size_t)b * 32 + h) << 10) + qt * 64) * 64;
  const unsigned short* Kb = Kw + (((size_t)b * 8 + g) << 16);  // *1024*64
  const unsigned short* Vb = Vw + (((size_t)b * 8 + g) << 16);
  const int wave = tid >> 6, lane = tid & 63;
  const int lrow = lane & 15, quad = lane >> 4;

  stage_tile<64>(Qb, 64, sQ, tid);
  __syncthreads();
  bf16_8 aq[2];
  {
    int r = wave * 16 + lrow;  // A-operand: m = lane&15
    aq[0] = *(const bf16_8*)(sQ + r * 64 + ((quad) ^ (r & 7)) * 8);
    aq[1] = *(const bf16_8*)(sQ + r * 64 + ((4 + quad) ^ (r & 7)) * 8);
  }

  float m_r[4], l_r[4];
  f32x4 o[4] = {};
#pragma unroll
  for (int r = 0; r < 4; ++r) { m_r[r] = -INFINITY; l_r[r] = 0.f; }

  for (int kc = 0; kc <= qt; ++kc) {
    __syncthreads();  // prev chunk's LDS reads done
    stage_tile<64>(Kb + (size_t)kc * 64 * 64, 64, sK, tid);
    // V chunk transposed into sVt[d][kv] (swizzled) for the PV B-operand
#pragma unroll
    for (int i = 0; i < 2; ++i) {
      int c = tid + i * 256;
      int r = c >> 3, cg = c & 7;
      union { uint4 u; unsigned short hh[8]; } t;
      t.u = *(const uint4*)(Vb + ((size_t)(kc * 64 + r)) * 64 + cg * 8);
#pragma unroll
      for (int jj = 0; jj < 8; ++jj) {
        int d = cg * 8 + jj;
        sVt[d * 64 + (((r >> 3) ^ (d & 7)) << 3) + (r & 7)] = t.hh[jj];
      }
    }
    __syncthreads();

    // S = Q K^T (16 q-rows x 64 kv-cols per wave)
    f32x4 sc[4] = {};
#pragma unroll
    for (int ks = 0; ks < 2; ++ks)
#pragma unroll
      for (int j = 0; j < 4; ++j) {
        int rk = j * 16 + lrow;  // B-operand: n = lane&15 -> kv row
        bf16_8 bk8 = *(const bf16_8*)(sK + rk * 64 + (((ks << 2) + quad) ^ (rk & 7)) * 8);
        sc[j] = __builtin_amdgcn_mfma_f32_16x16x32_bf16(aq[ks], bk8, sc[j], 0, 0, 0);
      }

    // scale + causal mask; C layout: row=quad*4+r, col=lane&15
    const int qrow_base = qt * 64 + wave * 16 + quad * 4;
    float rowmax[4];
#pragma unroll
    for (int r = 0; r < 4; ++r) rowmax[r] = -INFINITY;
#pragma unroll
    for (int j = 0; j < 4; ++j)
#pragma unroll
      for (int r = 0; r < 4; ++r) {
        float v = sc[j][r] * 0.125f;  // HEAD_DIM^-0.5
        int kcol = kc * 64 + j * 16 + lrow;
        if (kcol > qrow_base + r) v = -INFINITY;
        sc[j][r] = v;
        rowmax[r] = fmaxf(rowmax[r], v);
      }
    // online softmax update (state replicated across the 16 lanes of a row)
#pragma unroll
    for (int r = 0; r < 4; ++r) {
#pragma unroll
      for (int off = 1; off < 16; off <<= 1)
        rowmax[r] = fmaxf(rowmax[r], __shfl_xor(rowmax[r], off, 64));
      float mnew = fmaxf(m_r[r], rowmax[r]);
      float alpha = __expf(m_r[r] - mnew);  // first chunk: exp(-inf)=0
      m_r[r] = mnew;
      l_r[r] *= alpha;
      o[0][r] *= alpha; o[1][r] *= alpha; o[2][r] *= alpha; o[3][r] *= alpha;
    }
    float rowsum[4] = {0.f, 0.f, 0.f, 0.f};
#pragma unroll
    for (int j = 0; j < 4; ++j)
#pragma unroll
      for (int r = 0; r < 4; ++r) {
        float p = __expf(sc[j][r] - m_r[r]);  // masked: exp(-inf)=0
        rowsum[r] += p;
        int prow = wave * 16 + quad * 4 + r;
        int pcol = j * 16 + lrow;
        sP[prow * 64 + (((pcol >> 3) ^ (prow & 7)) << 3) + (pcol & 7)] = f2bf(p);
      }
#pragma unroll
    for (int r = 0; r < 4; ++r) {
#pragma unroll
      for (int off = 1; off < 16; off <<= 1)
        rowsum[r] += __shfl_xor(rowsum[r], off, 64);
      l_r[r] += rowsum[r];
    }
    __syncthreads();  // P cross-lane visible before A-operand reads

    // O += P V  (A = P rows from LDS, B = Vt rows)
#pragma unroll
    for (int ks = 0; ks < 2; ++ks) {
      int rp = wave * 16 + lrow;
      bf16_8 ap = *(const bf16_8*)(sP + rp * 64 + (((ks << 2) + quad) ^ (rp & 7)) * 8);
#pragma unroll
      for (int j = 0; j < 4; ++j) {
        int d = j * 16 + lrow;
        bf16_8 bv8 = *(const bf16_8*)(sVt + d * 64 + (((ks << 2) + quad) ^ (d & 7)) * 8);
        o[j] = __builtin_amdgcn_mfma_f32_16x16x32_bf16(ap, bv8, o[j], 0, 0, 0);
      }
    }
  }

  // epilogue: O/l -> a_ws[b, s, h*64+d] (bf16, feeds out_gemm)
#pragma unroll
  for (int r = 0; r < 4; ++r) {
    float inv = 1.f / l_r[r];
    int srow = qt * 64 + wave * 16 + quad * 4 + r;
    size_t base = ((((size_t)b << 10) + srow) << 11) + h * 64;
#pragma unroll
    for (int j = 0; j < 4; ++j)
      Ow[base + j * 16 + lrow] = f2bf(o[j][r] * inv);
  }
}

// ---------------- kernel 3: output projection (f32 out) ----------------
__global__ void __launch_bounds__(256)
out_gemm(const unsigned short* __restrict__ X, const unsigned short* __restrict__ Wo,
         const float* __restrict__ bo, float* __restrict__ out) {
  __shared__ unsigned short sA[128 * 64], sB[128 * 64];
  const int tid = threadIdx.x;
  const int tileM = blockIdx.x * 128, tileN = blockIdx.y * 128;
  f32x4 acc[4][4] = {};
  gemm_core(X + (size_t)tileM * 2048, Wo + (size_t)tileN * 2048, 2048, tid, sA, sB, acc);
  const int wave = tid >> 6, lane = tid & 63;
  const int wm = (wave >> 1) << 6, wn = (wave & 1) << 6;
  const int lrow = lane & 15, quad = lane >> 4;
#pragma unroll
  for (int i = 0; i < 4; ++i)
#pragma unroll
    for (int j = 0; j < 4; ++j)
#pragma unroll
      for (int r = 0; r < 4; ++r) {
        int m = tileM + wm + i * 16 + quad * 4 + r;
        int n = tileN + wn + j * 16 + lrow;
        out[(size_t)m * 2048 + n] = acc[i][j][r] + bo[n];
      }
}

extern "C" void kernel_launch(void* const* d_in, const int* in_sizes, int n_in,
                              void* d_out, int out_size, void* d_ws, size_t ws_size,
                              hipStream_t stream) {
  const float* x  = (const float*)d_in[0];
  // d_in[1] = mask (ignored; causal computed from indices)
  const float* Wq = (const float*)d_in[2];
  const float* bq = (const float*)d_in[3];
  const float* Wk = (const float*)d_in[4];
  const float* bk = (const float*)d_in[5];
  const float* Wv = (const float*)d_in[6];
  const float* bv = (const float*)d_in[7];
  const float* Wo = (const float*)d_in[8];
  const float* bo = (const float*)d_in[9];

  // bf16 workspace layout (elements):
  unsigned short* xbf  = (unsigned short*)d_ws;                  // 4,194,304
  unsigned short* wqbf = xbf  + (size_t)4194304;                 // 4,194,304
  unsigned short* wkbf = wqbf + (size_t)4194304;                 // 1,048,576
  unsigned short* wvbf = wkbf + (size_t)1048576;                 // 1,048,576
  unsigned short* wobf = wvbf + (size_t)1048576;                 // 4,194,304
  unsigned short* qws  = wobf + (size_t)4194304;                 // [2,32,1024,64]
  unsigned short* kws  = qws  + (size_t)2 * 32 * 1024 * 64;      // [2,8,1024,64]
  unsigned short* vws  = kws  + (size_t)2 * 8 * 1024 * 64;       // [2,8,1024,64]
  unsigned short* aws  = vws  + (size_t)2 * 8 * 1024 * 64;       // [2,1024,2048]
  float* out = (float*)d_out;

  hipLaunchKernelGGL(cvt_kernel, dim3(4096, 5), dim3(256), 0, stream,
                     x, Wq, Wk, Wv, Wo, xbf, wqbf, wkbf, wvbf, wobf);
  hipLaunchKernelGGL(qkv_gemm, dim3(16, 24), dim3(256), 0, stream,
                     xbf, wqbf, bq, wkbf, bk, wvbf, bv, qws, kws, vws);
  hipLaunchKernelGGL(attn_kernel, dim3(16, 32, 2), dim3(256), 0, stream,
                     qws, kws, vws, aws);
  hipLaunchKernelGGL(out_gemm, dim3(16, 16), dim3(256), 0, stream,
                     aws, wobf, bo, out);
}

// Round 3
// 231.676 us; speedup vs baseline: 1.1957x; 1.1957x over previous
//
#include <hip/hip_runtime.h>
#include <stdint.h>

// GQA fused forward: B=2, S=1024, HIDDEN=2048, H=32, G=8, D=64, causal.
// I/O float32; internal bf16 MFMA. Mask input ignored (causal from indices).
//
// Pipeline:
//   0) cvt:       f32 -> bf16 copies of x, Wq, Wk, Wv, Wo
//   1) qkv_gemm:  -> q_ws[b,h,s,d], k_ws[b,g,s,d], v_ws[b,g,d,s] (V TRANSPOSED)
//   2) attn:      S^T-form flash attention, paired q-tiles (qt,15-qt) per block
//   3) out_gemm:  a_ws @ Wo^T + bo -> d_out (f32)

typedef __bf16 bf16_8 __attribute__((ext_vector_type(8)));
typedef float f32x4 __attribute__((ext_vector_type(4)));

__device__ __forceinline__ unsigned short f2bf(float f) {
  union { float f; unsigned int i; } c; c.f = f;
  unsigned int u = c.i;
  return (unsigned short)((u + 0x7fffu + ((u >> 16) & 1u)) >> 16);
}

__device__ __forceinline__ void gl2lds16(const void* g, void* l) {
  __builtin_amdgcn_global_load_lds(
      (const __attribute__((address_space(1))) void*)g,
      (__attribute__((address_space(3))) void*)l, 16, 0, 0);
}

// Stage ROWS x 64 bf16 tile (leading dim ldg) into LDS; per-row XOR swizzle of
// 8-elem groups: phys_group = log_group ^ (row&7). 256 threads.
template <int ROWS>
__device__ __forceinline__ void stage_tile(const unsigned short* g, int ldg,
                                           unsigned short* lds, int tid) {
#pragma unroll
  for (int i = 0; i < ROWS * 8 / 256; ++i) {
    int c = tid + i * 256;
    int r = c >> 3;
    int grp = (c & 7) ^ (r & 7);
    gl2lds16(g + (size_t)r * ldg + grp * 8, lds + c * 8);
  }
}

// Core 128x128 GEMM tile: Y = X[128,K] @ W[128,K]^T into acc[4][4].
__device__ __forceinline__ void gemm_core(const unsigned short* Xt,
                                          const unsigned short* Wt, int K,
                                          int tid, unsigned short* sA,
                                          unsigned short* sB, f32x4 acc[4][4]) {
  const int wave = tid >> 6, lane = tid & 63;
  const int wm = (wave >> 1) << 6, wn = (wave & 1) << 6;
  const int lrow = lane & 15, quad = lane >> 4;
  for (int k0 = 0; k0 < K; k0 += 64) {
    __syncthreads();
    stage_tile<128>(Xt + k0, K, sA, tid);
    stage_tile<128>(Wt + k0, K, sB, tid);
    __syncthreads();
#pragma unroll
    for (int ks = 0; ks < 2; ++ks) {
      bf16_8 af[4], bw[4];
#pragma unroll
      for (int i = 0; i < 4; ++i) {
        int ra = wm + i * 16 + lrow;
        af[i] = *(const bf16_8*)(sA + ra * 64 + (((ks << 2) + quad) ^ (ra & 7)) * 8);
        int rb = wn + i * 16 + lrow;
        bw[i] = *(const bf16_8*)(sB + rb * 64 + (((ks << 2) + quad) ^ (rb & 7)) * 8);
      }
#pragma unroll
      for (int i = 0; i < 4; ++i)
#pragma unroll
        for (int j = 0; j < 4; ++j)
          acc[i][j] = __builtin_amdgcn_mfma_f32_16x16x32_bf16(af[i], bw[j],
                                                              acc[i][j], 0, 0, 0);
    }
  }
}

// ---------------- kernel 0: f32 -> bf16 conversion ----------------
__global__ void __launch_bounds__(256)
cvt_kernel(const float* __restrict__ s0, const float* __restrict__ s1,
           const float* __restrict__ s2, const float* __restrict__ s3,
           const float* __restrict__ s4,
           unsigned short* __restrict__ d0, unsigned short* __restrict__ d1,
           unsigned short* __restrict__ d2, unsigned short* __restrict__ d3,
           unsigned short* __restrict__ d4) {
  const float* src; unsigned short* dst; int n;
  switch (blockIdx.y) {
    case 0:  src = s0; dst = d0; n = 4194304; break;
    case 1:  src = s1; dst = d1; n = 4194304; break;
    case 2:  src = s2; dst = d2; n = 1048576; break;
    case 3:  src = s3; dst = d3; n = 1048576; break;
    default: src = s4; dst = d4; n = 4194304; break;
  }
  int idx = (blockIdx.x * 256 + threadIdx.x) * 4;
  if (idx >= n) return;
  float4 v = *(const float4*)(src + idx);
  ushort4 o;
  o.x = f2bf(v.x); o.y = f2bf(v.y); o.z = f2bf(v.z); o.w = f2bf(v.w);
  *(ushort4*)(dst + idx) = o;
}

// ---------------- kernel 1: fused QKV projection ----------------
// grid (16, 24). V is written TRANSPOSED: vws[b, g, d, s].
__global__ void __launch_bounds__(256)
qkv_gemm(const unsigned short* __restrict__ X,
         const unsigned short* __restrict__ Wq, const float* __restrict__ bq,
         const unsigned short* __restrict__ Wk, const float* __restrict__ bk,
         const unsigned short* __restrict__ Wv, const float* __restrict__ bv,
         unsigned short* __restrict__ qws, unsigned short* __restrict__ kws,
         unsigned short* __restrict__ vws) {
  __shared__ unsigned short sA[128 * 64], sB[128 * 64];
  const int tid = threadIdx.x;
  const int tileM = blockIdx.x * 128;
  const int ty = blockIdx.y;
  const unsigned short* W;
  const float* bias;
  unsigned short* outp;
  int nbase, nh;
  bool vt = false;
  if (ty < 16)      { W = Wq; bias = bq; outp = qws; nbase = ty * 128;        nh = 32; }
  else if (ty < 20) { W = Wk; bias = bk; outp = kws; nbase = (ty - 16) * 128; nh = 8; }
  else              { W = Wv; bias = bv; outp = vws; nbase = (ty - 20) * 128; nh = 8; vt = true; }

  f32x4 acc[4][4] = {};
  gemm_core(X + (size_t)tileM * 2048, W + (size_t)nbase * 2048, 2048, tid, sA, sB, acc);

  const int wave = tid >> 6, lane = tid & 63;
  const int wm = (wave >> 1) << 6, wn = (wave & 1) << 6;
  const int lrow = lane & 15, quad = lane >> 4;
#pragma unroll
  for (int i = 0; i < 4; ++i)
#pragma unroll
    for (int j = 0; j < 4; ++j)
#pragma unroll
      for (int r = 0; r < 4; ++r) {
        int m = tileM + wm + i * 16 + quad * 4 + r;   // row = m (s index)
        int n = nbase + wn + j * 16 + lrow;           // col = n (head*64+d)
        float v = acc[i][j][r] + bias[n];
        int b = m >> 10, s = m & 1023, h = n >> 6, d = n & 63;
        if (vt)
          outp[((((size_t)b * 8 + h) * 64 + d) << 10) + s] = f2bf(v);
        else
          outp[((((size_t)b * nh + h) << 10) + s) * 64 + d] = f2bf(v);
      }
}

// ---------------- kernel 2: causal flash attention (S^T form) ----------------
// grid (8, 32, 2): (pair, head, batch). Block handles q-tiles {x, 15-x} (64 rows
// each) -> uniform 17 chunk-units/block. Wave w owns q-cols [16w,16w+16).
// S^T = K.Q^T: C-layout col = q = lane&15 -> softmax state is PER-LANE.
// P^T stored to per-wave sPt region via swizzled b64 (same-wave, no barrier).
// V comes pre-transposed: Vt[b,g,d,s].
__global__ void __launch_bounds__(256)
attn_kernel(const unsigned short* __restrict__ Qw, const unsigned short* __restrict__ Kw,
            const unsigned short* __restrict__ Vt, unsigned short* __restrict__ Ow) {
  __shared__ unsigned short sQ[64 * 64], sK[64 * 64], sVt[64 * 64], sPt[64 * 64];
  const int tid = threadIdx.x;
  const int pair = blockIdx.x, h = blockIdx.y, b = blockIdx.z;
  const int g = h >> 2;
  const unsigned short* Kb = Kw + (((size_t)b * 8 + g) << 16);  // [s][d]
  const unsigned short* Vb = Vt + (((size_t)b * 8 + g) << 16);  // [d][s], ld=1024
  const int wave = tid >> 6, lane = tid & 63;
  const int lrow = lane & 15, quad = lane >> 4;
  const int qloc = wave * 16 + lrow;
  const float C = 0.18033688f;  // 0.125 * log2(e)

#pragma unroll 1
  for (int t = 0; t < 2; ++t) {
    const int qt = t ? (15 - pair) : pair;
    __syncthreads();  // protect all LDS from previous phase readers
    stage_tile<64>(Qw + ((((size_t)b * 32 + h) << 10) + qt * 64) * 64, 64, sQ, tid);
    __syncthreads();
    bf16_8 qf[2];  // Q as B-operand: n = q = qloc, k-halves over d
#pragma unroll
    for (int kh = 0; kh < 2; ++kh)
      qf[kh] = *(const bf16_8*)(sQ + qloc * 64 + (((kh << 2) + quad) ^ (qloc & 7)) * 8);

    float m_i = -INFINITY, l_i = 0.f;
    f32x4 o[4] = {};
    const int q_g = qt * 64 + qloc;

    for (int kc = 0; kc <= qt; ++kc) {
      __syncthreads();  // prev chunk's sK/sVt reads done
      stage_tile<64>(Kb + (size_t)kc * 64 * 64, 64, sK, tid);
      stage_tile<64>(Vb + kc * 64, 1024, sVt, tid);
      __syncthreads();

      // S^T = K . Q^T : 4 kv m-tiles x (K=64 via 2 halves)
      f32x4 sc[4] = {};
#pragma unroll
      for (int kh = 0; kh < 2; ++kh)
#pragma unroll
        for (int mt = 0; mt < 4; ++mt) {
          int kv = mt * 16 + lrow;
          bf16_8 kf = *(const bf16_8*)(sK + kv * 64 + (((kh << 2) + quad) ^ (kv & 7)) * 8);
          sc[mt] = __builtin_amdgcn_mfma_f32_16x16x32_bf16(kf, qf[kh], sc[mt], 0, 0, 0);
        }

      // mask + per-lane max (C layout: row kv = mt*16 + quad*4 + r, col q = lrow)
      const int kvb = kc * 64 + quad * 4;
      float mx = -INFINITY;
#pragma unroll
      for (int mt = 0; mt < 4; ++mt)
#pragma unroll
        for (int r = 0; r < 4; ++r) {
          float v = sc[mt][r];
          if (kvb + mt * 16 + r > q_g) v = -INFINITY;
          sc[mt][r] = v;
          mx = fmaxf(mx, v);
        }
      mx = fmaxf(mx, __shfl_xor(mx, 16));
      mx = fmaxf(mx, __shfl_xor(mx, 32));
      float mnew = fmaxf(m_i, mx);
      float alpha = exp2f((m_i - mnew) * C);
      m_i = mnew;
      float sum = 0.f;
#pragma unroll
      for (int mt = 0; mt < 4; ++mt)
#pragma unroll
        for (int r = 0; r < 4; ++r) {
          float p = exp2f((sc[mt][r] - m_i) * C);
          sc[mt][r] = p;
          sum += p;
        }
      sum += __shfl_xor(sum, 16);
      sum += __shfl_xor(sum, 32);
      l_i = l_i * alpha + sum;
#pragma unroll
      for (int mt = 0; mt < 4; ++mt)
#pragma unroll
        for (int r = 0; r < 4; ++r) o[mt][r] *= alpha;

      // P^T -> sPt[q][kv] (truncation-round bf16, packed b64, grp4 xor swizzle)
#pragma unroll
      for (int mt = 0; mt < 4; ++mt) {
        unsigned int a0 = __float_as_uint(sc[mt][0]), a1 = __float_as_uint(sc[mt][1]);
        unsigned int a2 = __float_as_uint(sc[mt][2]), a3 = __float_as_uint(sc[mt][3]);
        uint2 pk;
        pk.x = (a0 >> 16) | (a1 & 0xffff0000u);
        pk.y = (a2 >> 16) | (a3 & 0xffff0000u);
        int grp = (mt * 4 + quad) ^ lrow;
        *(uint2*)(sPt + qloc * 64 + grp * 4) = pk;
      }

      // O^T += V^T . P^T  (A = sVt rows, B = sPt rows; same-wave P, no barrier)
#pragma unroll
      for (int kh = 0; kh < 2; ++kh) {
        int gbase = kh * 8 + quad * 2;
        uint2 b0 = *(const uint2*)(sPt + qloc * 64 + ((gbase) ^ lrow) * 4);
        uint2 b1 = *(const uint2*)(sPt + qloc * 64 + ((gbase + 1) ^ lrow) * 4);
        union { uint4 u; bf16_8 v; } bb;
        bb.u = make_uint4(b0.x, b0.y, b1.x, b1.y);
#pragma unroll
        for (int mt = 0; mt < 4; ++mt) {
          int d = mt * 16 + lrow;
          bf16_8 vf = *(const bf16_8*)(sVt + d * 64 + (((kh << 2) + quad) ^ (d & 7)) * 8);
          o[mt] = __builtin_amdgcn_mfma_f32_16x16x32_bf16(vf, bb.v, o[mt], 0, 0, 0);
        }
      }
    }

    // epilogue: O^T -> sPt (reused as sO[q][d]) -> coalesced global store
    float inv = 1.f / l_i;
#pragma unroll
    for (int mt = 0; mt < 4; ++mt) {
      uint2 pk;
      pk.x = f2bf(o[mt][0] * inv) | ((unsigned int)f2bf(o[mt][1] * inv) << 16);
      pk.y = f2bf(o[mt][2] * inv) | ((unsigned int)f2bf(o[mt][3] * inv) << 16);
      int grp = (mt * 4 + quad) ^ lrow;
      *(uint2*)(sPt + qloc * 64 + grp * 4) = pk;
    }
    __syncthreads();
    {
      int row = tid >> 2, seg = tid & 3;
      uint2 w0 = *(const uint2*)(sPt + row * 64 + ((seg * 4 + 0) ^ (row & 15)) * 4);
      uint2 w1 = *(const uint2*)(sPt + row * 64 + ((seg * 4 + 1) ^ (row & 15)) * 4);
      uint2 w2 = *(const uint2*)(sPt + row * 64 + ((seg * 4 + 2) ^ (row & 15)) * 4);
      uint2 w3 = *(const uint2*)(sPt + row * 64 + ((seg * 4 + 3) ^ (row & 15)) * 4);
      size_t base = ((((size_t)b << 10) + qt * 64 + row) << 11) + h * 64 + seg * 16;
      *(uint4*)(Ow + base) = make_uint4(w0.x, w0.y, w1.x, w1.y);
      *(uint4*)(Ow + base + 8) = make_uint4(w2.x, w2.y, w3.x, w3.y);
    }
  }
}

// ---------------- kernel 3: output projection (f32 out) ----------------
__global__ void __launch_bounds__(256)
out_gemm(const unsigned short* __restrict__ X, const unsigned short* __restrict__ Wo,
         const float* __restrict__ bo, float* __restrict__ out) {
  __shared__ unsigned short sA[128 * 64], sB[128 * 64];
  const int tid = threadIdx.x;
  const int tileM = blockIdx.x * 128, tileN = blockIdx.y * 128;
  f32x4 acc[4][4] = {};
  gemm_core(X + (size_t)tileM * 2048, Wo + (size_t)tileN * 2048, 2048, tid, sA, sB, acc);
  const int wave = tid >> 6, lane = tid & 63;
  const int wm = (wave >> 1) << 6, wn = (wave & 1) << 6;
  const int lrow = lane & 15, quad = lane >> 4;
#pragma unroll
  for (int i = 0; i < 4; ++i)
#pragma unroll
    for (int j = 0; j < 4; ++j)
#pragma unroll
      for (int r = 0; r < 4; ++r) {
        int m = tileM + wm + i * 16 + quad * 4 + r;
        int n = tileN + wn + j * 16 + lrow;
        out[(size_t)m * 2048 + n] = acc[i][j][r] + bo[n];
      }
}

extern "C" void kernel_launch(void* const* d_in, const int* in_sizes, int n_in,
                              void* d_out, int out_size, void* d_ws, size_t ws_size,
                              hipStream_t stream) {
  const float* x  = (const float*)d_in[0];
  const float* Wq = (const float*)d_in[2];
  const float* bq = (const float*)d_in[3];
  const float* Wk = (const float*)d_in[4];
  const float* bk = (const float*)d_in[5];
  const float* Wv = (const float*)d_in[6];
  const float* bv = (const float*)d_in[7];
  const float* Wo = (const float*)d_in[8];
  const float* bo = (const float*)d_in[9];

  unsigned short* xbf  = (unsigned short*)d_ws;                  // 4,194,304
  unsigned short* wqbf = xbf  + (size_t)4194304;
  unsigned short* wkbf = wqbf + (size_t)4194304;
  unsigned short* wvbf = wkbf + (size_t)1048576;
  unsigned short* wobf = wvbf + (size_t)1048576;
  unsigned short* qws  = wobf + (size_t)4194304;                 // [2,32,1024,64]
  unsigned short* kws  = qws  + (size_t)2 * 32 * 1024 * 64;      // [2,8,1024,64]
  unsigned short* vws  = kws  + (size_t)2 * 8 * 1024 * 64;      // [2,8,64,1024] (d-major!)
  unsigned short* aws  = vws  + (size_t)2 * 8 * 1024 * 64;      // [2,1024,2048]
  float* out = (float*)d_out;

  hipLaunchKernelGGL(cvt_kernel, dim3(4096, 5), dim3(256), 0, stream,
                     x, Wq, Wk, Wv, Wo, xbf, wqbf, wkbf, wvbf, wobf);
  hipLaunchKernelGGL(qkv_gemm, dim3(16, 24), dim3(256), 0, stream,
                     xbf, wqbf, bq, wkbf, bk, wvbf, bv, qws, kws, vws);
  hipLaunchKernelGGL(attn_kernel, dim3(8, 32, 2), dim3(256), 0, stream,
                     qws, kws, vws, aws);
  hipLaunchKernelGGL(out_gemm, dim3(16, 16), dim3(256), 0, stream,
                     aws, wobf, bo, out);
}

// Round 4
// 218.494 us; speedup vs baseline: 1.2678x; 1.0603x over previous
//
#include <hip/hip_runtime.h>
#include <stdint.h>

// GQA fused forward: B=2, S=1024, HIDDEN=2048, H=32, G=8, D=64, causal.
// I/O float32; internal bf16 MFMA. Mask input ignored (causal from indices).
//
// Pipeline:
//   0) cvt:         f32 -> bf16 copies of x, Wq, Wk, Wv, Wo
//   1) qkv_gemm:    split-K=2 (768 blocks, 3/CU) -> bf16 partials pq[2][2048][3072]
//   2) qkv_reduce:  sum halves + bias -> q_ws[b,h,s,d], k_ws[b,g,s,d], v_ws[b,g,d,s]
//   3) attn:        S^T-form flash attention, paired q-tiles -> a_ws (bf16)
//   4) out_gemm:    split-K=2 (512 blocks, 2/CU) -> bf16 partials po[2][2048][2048]
//   5) out_reduce:  sum halves + bo -> d_out (f32)
//
// Split-K rationale: R3 profile showed qkv_gemm at 384 blocks = 1.5 blocks/CU,
// Occupancy 13%, 505 TF (m97 structure needs ~3 blocks/CU to hide barrier
// drains -> 912 TF). Split-K doubles blocks while keeping the 128x128 tile.

typedef __bf16 bf16_8 __attribute__((ext_vector_type(8)));
typedef float f32x4 __attribute__((ext_vector_type(4)));

__device__ __forceinline__ unsigned short f2bf(float f) {
  union { float f; unsigned int i; } c; c.f = f;
  unsigned int u = c.i;
  return (unsigned short)((u + 0x7fffu + ((u >> 16) & 1u)) >> 16);
}
__device__ __forceinline__ float bfbits2f(unsigned int lo16) {
  union { unsigned int i; float f; } c; c.i = lo16 << 16; return c.f;
}

__device__ __forceinline__ void gl2lds16(const void* g, void* l) {
  __builtin_amdgcn_global_load_lds(
      (const __attribute__((address_space(1))) void*)g,
      (__attribute__((address_space(3))) void*)l, 16, 0, 0);
}

// Stage ROWS x 64 bf16 tile (leading dim ldg) into LDS; per-row XOR swizzle of
// 8-elem groups: phys_group = log_group ^ (row&7). 256 threads.
template <int ROWS>
__device__ __forceinline__ void stage_tile(const unsigned short* g, int ldg,
                                           unsigned short* lds, int tid) {
#pragma unroll
  for (int i = 0; i < ROWS * 8 / 256; ++i) {
    int c = tid + i * 256;
    int r = c >> 3;
    int grp = (c & 7) ^ (r & 7);
    gl2lds16(g + (size_t)r * ldg + grp * 8, lds + c * 8);
  }
}

// Core 128x128 GEMM tile: Y = X[128,kiter] @ W[128,kiter]^T (leading dim ld).
__device__ __forceinline__ void gemm_core(const unsigned short* Xt,
                                          const unsigned short* Wt, int kiter,
                                          int ld, int tid, unsigned short* sA,
                                          unsigned short* sB, f32x4 acc[4][4]) {
  const int wave = tid >> 6, lane = tid & 63;
  const int wm = (wave >> 1) << 6, wn = (wave & 1) << 6;
  const int lrow = lane & 15, quad = lane >> 4;
  for (int k0 = 0; k0 < kiter; k0 += 64) {
    __syncthreads();
    stage_tile<128>(Xt + k0, ld, sA, tid);
    stage_tile<128>(Wt + k0, ld, sB, tid);
    __syncthreads();
#pragma unroll
    for (int ks = 0; ks < 2; ++ks) {
      bf16_8 af[4], bw[4];
#pragma unroll
      for (int i = 0; i < 4; ++i) {
        int ra = wm + i * 16 + lrow;
        af[i] = *(const bf16_8*)(sA + ra * 64 + (((ks << 2) + quad) ^ (ra & 7)) * 8);
        int rb = wn + i * 16 + lrow;
        bw[i] = *(const bf16_8*)(sB + rb * 64 + (((ks << 2) + quad) ^ (rb & 7)) * 8);
      }
#pragma unroll
      for (int i = 0; i < 4; ++i)
#pragma unroll
        for (int j = 0; j < 4; ++j)
          acc[i][j] = __builtin_amdgcn_mfma_f32_16x16x32_bf16(af[i], bw[j],
                                                              acc[i][j], 0, 0, 0);
    }
  }
}

// ---------------- kernel 0: f32 -> bf16 conversion ----------------
__global__ void __launch_bounds__(256)
cvt_kernel(const float* __restrict__ s0, const float* __restrict__ s1,
           const float* __restrict__ s2, const float* __restrict__ s3,
           const float* __restrict__ s4,
           unsigned short* __restrict__ d0, unsigned short* __restrict__ d1,
           unsigned short* __restrict__ d2, unsigned short* __restrict__ d3,
           unsigned short* __restrict__ d4) {
  const float* src; unsigned short* dst; int n;
  switch (blockIdx.y) {
    case 0:  src = s0; dst = d0; n = 4194304; break;
    case 1:  src = s1; dst = d1; n = 4194304; break;
    case 2:  src = s2; dst = d2; n = 1048576; break;
    case 3:  src = s3; dst = d3; n = 1048576; break;
    default: src = s4; dst = d4; n = 4194304; break;
  }
  int idx = (blockIdx.x * 256 + threadIdx.x) * 4;
  if (idx >= n) return;
  float4 v = *(const float4*)(src + idx);
  ushort4 o;
  o.x = f2bf(v.x); o.y = f2bf(v.y); o.z = f2bf(v.z); o.w = f2bf(v.w);
  *(ushort4*)(dst + idx) = o;
}

// ---------------- kernel 1: QKV projection, split-K=2 ----------------
// grid (16, 24, 2): m-tile, n-tile over [Q|K|V] (global n = ty*128), K-half.
// Writes bf16 partials pq[z][m][n] (no bias here).
__global__ void __launch_bounds__(256)
qkv_gemm(const unsigned short* __restrict__ X,
         const unsigned short* __restrict__ Wq,
         const unsigned short* __restrict__ Wk,
         const unsigned short* __restrict__ Wv,
         unsigned short* __restrict__ pq) {
  __shared__ unsigned short sA[128 * 64], sB[128 * 64];
  const int tid = threadIdx.x;
  const int tileM = blockIdx.x * 128;
  const int ty = blockIdx.y, z = blockIdx.z;
  const unsigned short* W;
  if (ty < 16)      W = Wq + (size_t)ty * 128 * 2048;
  else if (ty < 20) W = Wk + (size_t)(ty - 16) * 128 * 2048;
  else              W = Wv + (size_t)(ty - 20) * 128 * 2048;
  const int ng = ty * 128;

  f32x4 acc[4][4] = {};
  gemm_core(X + (size_t)tileM * 2048 + z * 1024, W + z * 1024, 1024, 2048,
            tid, sA, sB, acc);

  unsigned short* dst = pq + (size_t)z * 2048 * 3072;
  const int wave = tid >> 6, lane = tid & 63;
  const int wm = (wave >> 1) << 6, wn = (wave & 1) << 6;
  const int lrow = lane & 15, quad = lane >> 4;
#pragma unroll
  for (int i = 0; i < 4; ++i)
#pragma unroll
    for (int j = 0; j < 4; ++j)
#pragma unroll
      for (int r = 0; r < 4; ++r) {
        int m = tileM + wm + i * 16 + quad * 4 + r;
        int n = ng + wn + j * 16 + lrow;
        dst[(size_t)m * 3072 + n] = f2bf(acc[i][j][r]);
      }
}

// ---------------- kernel 1b: QKV reduce + bias + scatter ----------------
// grid (2048), block 384: one m-row per block, 8 n's per thread.
__global__ void __launch_bounds__(384)
qkv_reduce(const unsigned short* __restrict__ pq,
           const float* __restrict__ bq, const float* __restrict__ bk,
           const float* __restrict__ bv,
           unsigned short* __restrict__ qws, unsigned short* __restrict__ kws,
           unsigned short* __restrict__ vws) {
  const int m = blockIdx.x;
  const int n = threadIdx.x * 8;
  uint4 p0 = *(const uint4*)(pq + (size_t)m * 3072 + n);
  uint4 p1 = *(const uint4*)(pq + (size_t)(2048 + m) * 3072 + n);
  const unsigned int* a = (const unsigned int*)&p0;
  const unsigned int* c = (const unsigned int*)&p1;
  float v[8];
#pragma unroll
  for (int i = 0; i < 4; ++i) {
    v[2 * i]     = bfbits2f(a[i] & 0xffffu) + bfbits2f(c[i] & 0xffffu);
    v[2 * i + 1] = bfbits2f(a[i] >> 16)     + bfbits2f(c[i] >> 16);
  }
  const int b = m >> 10, s = m & 1023;
  if (n < 2048) {
    int h = n >> 6, d = n & 63;
#pragma unroll
    for (int i = 0; i < 8; ++i) v[i] += bq[n + i];
    unsigned int o[4];
#pragma unroll
    for (int i = 0; i < 4; ++i)
      o[i] = f2bf(v[2 * i]) | ((unsigned int)f2bf(v[2 * i + 1]) << 16);
    *(uint4*)(qws + ((((size_t)b * 32 + h) << 10) + s) * 64 + d) =
        make_uint4(o[0], o[1], o[2], o[3]);
  } else if (n < 2560) {
    int nk = n - 2048, g = nk >> 6, d = nk & 63;
#pragma unroll
    for (int i = 0; i < 8; ++i) v[i] += bk[nk + i];
    unsigned int o[4];
#pragma unroll
    for (int i = 0; i < 4; ++i)
      o[i] = f2bf(v[2 * i]) | ((unsigned int)f2bf(v[2 * i + 1]) << 16);
    *(uint4*)(kws + ((((size_t)b * 8 + g) << 10) + s) * 64 + d) =
        make_uint4(o[0], o[1], o[2], o[3]);
  } else {
    int nv = n - 2560, g = nv >> 6, d0 = nv & 63;
#pragma unroll
    for (int i = 0; i < 8; ++i) {
      float val = v[i] + bv[nv + i];
      // transposed V: vws[b, g, d, s]
      vws[((((size_t)b * 8 + g) * 64 + d0 + i) << 10) + s] = f2bf(val);
    }
  }
}

// ---------------- kernel 2: causal flash attention (S^T form) ----------------
// grid (8, 32, 2): (pair, head, batch). Block handles q-tiles {x, 15-x}.
// S^T = K.Q^T -> softmax state per-lane (q = lane&15). V pre-transposed [b,g,d,s].
__global__ void __launch_bounds__(256)
attn_kernel(const unsigned short* __restrict__ Qw, const unsigned short* __restrict__ Kw,
            const unsigned short* __restrict__ Vt, unsigned short* __restrict__ Ow) {
  __shared__ unsigned short sQ[64 * 64], sK[64 * 64], sVt[64 * 64], sPt[64 * 64];
  const int tid = threadIdx.x;
  const int pair = blockIdx.x, h = blockIdx.y, b = blockIdx.z;
  const int g = h >> 2;
  const unsigned short* Kb = Kw + (((size_t)b * 8 + g) << 16);  // [s][d]
  const unsigned short* Vb = Vt + (((size_t)b * 8 + g) << 16);  // [d][s], ld=1024
  const int wave = tid >> 6, lane = tid & 63;
  const int lrow = lane & 15, quad = lane >> 4;
  const int qloc = wave * 16 + lrow;
  const float C = 0.18033688f;  // 0.125 * log2(e)

#pragma unroll 1
  for (int t = 0; t < 2; ++t) {
    const int qt = t ? (15 - pair) : pair;
    __syncthreads();
    stage_tile<64>(Qw + ((((size_t)b * 32 + h) << 10) + qt * 64) * 64, 64, sQ, tid);
    __syncthreads();
    bf16_8 qf[2];
#pragma unroll
    for (int kh = 0; kh < 2; ++kh)
      qf[kh] = *(const bf16_8*)(sQ + qloc * 64 + (((kh << 2) + quad) ^ (qloc & 7)) * 8);

    float m_i = -INFINITY, l_i = 0.f;
    f32x4 o[4] = {};
    const int q_g = qt * 64 + qloc;

    for (int kc = 0; kc <= qt; ++kc) {
      __syncthreads();
      stage_tile<64>(Kb + (size_t)kc * 64 * 64, 64, sK, tid);
      stage_tile<64>(Vb + kc * 64, 1024, sVt, tid);
      __syncthreads();

      f32x4 sc[4] = {};
#pragma unroll
      for (int kh = 0; kh < 2; ++kh)
#pragma unroll
        for (int mt = 0; mt < 4; ++mt) {
          int kv = mt * 16 + lrow;
          bf16_8 kf = *(const bf16_8*)(sK + kv * 64 + (((kh << 2) + quad) ^ (kv & 7)) * 8);
          sc[mt] = __builtin_amdgcn_mfma_f32_16x16x32_bf16(kf, qf[kh], sc[mt], 0, 0, 0);
        }

      const int kvb = kc * 64 + quad * 4;
      float mx = -INFINITY;
#pragma unroll
      for (int mt = 0; mt < 4; ++mt)
#pragma unroll
        for (int r = 0; r < 4; ++r) {
          float v = sc[mt][r];
          if (kvb + mt * 16 + r > q_g) v = -INFINITY;
          sc[mt][r] = v;
          mx = fmaxf(mx, v);
        }
      mx = fmaxf(mx, __shfl_xor(mx, 16));
      mx = fmaxf(mx, __shfl_xor(mx, 32));
      float mnew = fmaxf(m_i, mx);
      float alpha = exp2f((m_i - mnew) * C);
      m_i = mnew;
      float sum = 0.f;
#pragma unroll
      for (int mt = 0; mt < 4; ++mt)
#pragma unroll
        for (int r = 0; r < 4; ++r) {
          float p = exp2f((sc[mt][r] - m_i) * C);
          sc[mt][r] = p;
          sum += p;
        }
      sum += __shfl_xor(sum, 16);
      sum += __shfl_xor(sum, 32);
      l_i = l_i * alpha + sum;
#pragma unroll
      for (int mt = 0; mt < 4; ++mt)
#pragma unroll
        for (int r = 0; r < 4; ++r) o[mt][r] *= alpha;

#pragma unroll
      for (int mt = 0; mt < 4; ++mt) {
        unsigned int a0 = __float_as_uint(sc[mt][0]), a1 = __float_as_uint(sc[mt][1]);
        unsigned int a2 = __float_as_uint(sc[mt][2]), a3 = __float_as_uint(sc[mt][3]);
        uint2 pk;
        pk.x = (a0 >> 16) | (a1 & 0xffff0000u);
        pk.y = (a2 >> 16) | (a3 & 0xffff0000u);
        int grp = (mt * 4 + quad) ^ lrow;
        *(uint2*)(sPt + qloc * 64 + grp * 4) = pk;
      }

#pragma unroll
      for (int kh = 0; kh < 2; ++kh) {
        int gbase = kh * 8 + quad * 2;
        uint2 b0 = *(const uint2*)(sPt + qloc * 64 + ((gbase) ^ lrow) * 4);
        uint2 b1 = *(const uint2*)(sPt + qloc * 64 + ((gbase + 1) ^ lrow) * 4);
        union { uint4 u; bf16_8 v; } bb;
        bb.u = make_uint4(b0.x, b0.y, b1.x, b1.y);
#pragma unroll
        for (int mt = 0; mt < 4; ++mt) {
          int d = mt * 16 + lrow;
          bf16_8 vf = *(const bf16_8*)(sVt + d * 64 + (((kh << 2) + quad) ^ (d & 7)) * 8);
          o[mt] = __builtin_amdgcn_mfma_f32_16x16x32_bf16(vf, bb.v, o[mt], 0, 0, 0);
        }
      }
    }

    float inv = 1.f / l_i;
#pragma unroll
    for (int mt = 0; mt < 4; ++mt) {
      uint2 pk;
      pk.x = f2bf(o[mt][0] * inv) | ((unsigned int)f2bf(o[mt][1] * inv) << 16);
      pk.y = f2bf(o[mt][2] * inv) | ((unsigned int)f2bf(o[mt][3] * inv) << 16);
      int grp = (mt * 4 + quad) ^ lrow;
      *(uint2*)(sPt + qloc * 64 + grp * 4) = pk;
    }
    __syncthreads();
    {
      int row = tid >> 2, seg = tid & 3;
      uint2 w0 = *(const uint2*)(sPt + row * 64 + ((seg * 4 + 0) ^ (row & 15)) * 4);
      uint2 w1 = *(const uint2*)(sPt + row * 64 + ((seg * 4 + 1) ^ (row & 15)) * 4);
      uint2 w2 = *(const uint2*)(sPt + row * 64 + ((seg * 4 + 2) ^ (row & 15)) * 4);
      uint2 w3 = *(const uint2*)(sPt + row * 64 + ((seg * 4 + 3) ^ (row & 15)) * 4);
      size_t base = ((((size_t)b << 10) + qt * 64 + row) << 11) + h * 64 + seg * 16;
      *(uint4*)(Ow + base) = make_uint4(w0.x, w0.y, w1.x, w1.y);
      *(uint4*)(Ow + base + 8) = make_uint4(w2.x, w2.y, w3.x, w3.y);
    }
  }
}

// ---------------- kernel 3: output projection, split-K=2 ----------------
// grid (16, 16, 2) -> bf16 partials po[z][2048][2048].
__global__ void __launch_bounds__(256)
out_gemm(const unsigned short* __restrict__ X, const unsigned short* __restrict__ Wo,
         unsigned short* __restrict__ po) {
  __shared__ unsigned short sA[128 * 64], sB[128 * 64];
  const int tid = threadIdx.x;
  const int tileM = blockIdx.x * 128, tileN = blockIdx.y * 128;
  const int z = blockIdx.z;
  f32x4 acc[4][4] = {};
  gemm_core(X + (size_t)tileM * 2048 + z * 1024,
            Wo + (size_t)tileN * 2048 + z * 1024, 1024, 2048, tid, sA, sB, acc);
  unsigned short* dst = po + (size_t)z * 2048 * 2048;
  const int wave = tid >> 6, lane = tid & 63;
  const int wm = (wave >> 1) << 6, wn = (wave & 1) << 6;
  const int lrow = lane & 15, quad = lane >> 4;
#pragma unroll
  for (int i = 0; i < 4; ++i)
#pragma unroll
    for (int j = 0; j < 4; ++j)
#pragma unroll
      for (int r = 0; r < 4; ++r) {
        int m = tileM + wm + i * 16 + quad * 4 + r;
        int n = tileN + wn + j * 16 + lrow;
        dst[(size_t)m * 2048 + n] = f2bf(acc[i][j][r]);
      }
}

// ---------------- kernel 3b: out reduce + bias -> f32 ----------------
// grid (2048), block 256: one m-row per block, 8 n's per thread.
__global__ void __launch_bounds__(256)
out_reduce(const unsigned short* __restrict__ po, const float* __restrict__ bo,
           float* __restrict__ out) {
  const int m = blockIdx.x;
  const int n = threadIdx.x * 8;
  uint4 p0 = *(const uint4*)(po + (size_t)m * 2048 + n);
  uint4 p1 = *(const uint4*)(po + (size_t)(2048 + m) * 2048 + n);
  const unsigned int* a = (const unsigned int*)&p0;
  const unsigned int* c = (const unsigned int*)&p1;
  float v[8];
#pragma unroll
  for (int i = 0; i < 4; ++i) {
    v[2 * i]     = bfbits2f(a[i] & 0xffffu) + bfbits2f(c[i] & 0xffffu);
    v[2 * i + 1] = bfbits2f(a[i] >> 16)     + bfbits2f(c[i] >> 16);
  }
#pragma unroll
  for (int i = 0; i < 8; ++i) v[i] += bo[n + i];
  float4 o0 = make_float4(v[0], v[1], v[2], v[3]);
  float4 o1 = make_float4(v[4], v[5], v[6], v[7]);
  *(float4*)(out + (size_t)m * 2048 + n) = o0;
  *(float4*)(out + (size_t)m * 2048 + n + 4) = o1;
}

extern "C" void kernel_launch(void* const* d_in, const int* in_sizes, int n_in,
                              void* d_out, int out_size, void* d_ws, size_t ws_size,
                              hipStream_t stream) {
  const float* x  = (const float*)d_in[0];
  const float* Wq = (const float*)d_in[2];
  const float* bq = (const float*)d_in[3];
  const float* Wk = (const float*)d_in[4];
  const float* bk = (const float*)d_in[5];
  const float* Wv = (const float*)d_in[6];
  const float* bv = (const float*)d_in[7];
  const float* Wo = (const float*)d_in[8];
  const float* bo = (const float*)d_in[9];

  unsigned short* xbf  = (unsigned short*)d_ws;                  // 4,194,304 el
  unsigned short* wqbf = xbf  + (size_t)4194304;
  unsigned short* wkbf = wqbf + (size_t)4194304;
  unsigned short* wvbf = wkbf + (size_t)1048576;
  unsigned short* wobf = wvbf + (size_t)1048576;
  unsigned short* qws  = wobf + (size_t)4194304;                 // [2,32,1024,64]
  unsigned short* kws  = qws  + (size_t)2 * 32 * 1024 * 64;      // [2,8,1024,64]
  unsigned short* vws  = kws  + (size_t)2 * 8 * 1024 * 64;       // [2,8,64,1024]
  unsigned short* aws  = vws  + (size_t)2 * 8 * 1024 * 64;       // [2,1024,2048]
  unsigned short* pq   = aws  + (size_t)4194304;                 // [2,2048,3072]
  unsigned short* po   = pq;   // alias: pq dead after qkv_reduce, po smaller
  float* out = (float*)d_out;

  hipLaunchKernelGGL(cvt_kernel, dim3(4096, 5), dim3(256), 0, stream,
                     x, Wq, Wk, Wv, Wo, xbf, wqbf, wkbf, wvbf, wobf);
  hipLaunchKernelGGL(qkv_gemm, dim3(16, 24, 2), dim3(256), 0, stream,
                     xbf, wqbf, wkbf, wvbf, pq);
  hipLaunchKernelGGL(qkv_reduce, dim3(2048), dim3(384), 0, stream,
                     pq, bq, bk, bv, qws, kws, vws);
  hipLaunchKernelGGL(attn_kernel, dim3(8, 32, 2), dim3(256), 0, stream,
                     qws, kws, vws, aws);
  hipLaunchKernelGGL(out_gemm, dim3(16, 16, 2), dim3(256), 0, stream,
                     aws, wobf, po);
  hipLaunchKernelGGL(out_reduce, dim3(2048), dim3(256), 0, stream,
                     po, bo, out);
}